// Round 2
// 339.174 us; speedup vs baseline: 1.0464x; 1.0464x over previous
//
#include <hip/hip_runtime.h>
#include <stdint.h>

typedef unsigned short ushort_t;
typedef short bf16x8 __attribute__((ext_vector_type(8)));
typedef float f32x4 __attribute__((ext_vector_type(4)));
typedef ushort_t us2 __attribute__((ext_vector_type(2)));
typedef ushort_t us4 __attribute__((ext_vector_type(4)));
typedef ushort_t us8 __attribute__((ext_vector_type(8)));

__device__ __forceinline__ float b2f(ushort_t u) {
    union { unsigned int i; float f; } v; v.i = ((unsigned int)u) << 16; return v.f;
}
__device__ __forceinline__ ushort_t f2b(float f) {
    union { float f; unsigned int i; } v; v.f = f;
    unsigned int r = v.i + 0x7fffu + ((v.i >> 16) & 1u);
    return (ushort_t)(r >> 16);
}

typedef __attribute__((address_space(3))) unsigned int lds_u32;
typedef __attribute__((address_space(1))) const unsigned int gbl_u32;

__device__ __forceinline__ void gload_lds16(const void* g, void* l) {
    __builtin_amdgcn_global_load_lds((gbl_u32*)g, (lds_u32*)l, 16, 0, 0);
}

// ---------------------------------------------------------------------------
// fp32 -> bf16 elementwise convert, 8 elems/thread.
// ---------------------------------------------------------------------------
__global__ void cvt_f32_bf16(const float* __restrict__ src, ushort_t* __restrict__ dst, int n8)
{
    const int i = blockIdx.x * 256 + threadIdx.x;
    if (i >= n8) return;
    f32x4 a = *(const f32x4*)&src[i * 8];
    f32x4 b = *(const f32x4*)&src[i * 8 + 4];
    us8 o;
#pragma unroll
    for (int j = 0; j < 4; j++) { o[j] = f2b(a[j]); o[j + 4] = f2b(b[j]); }
    *(us8*)&dst[i * 8] = o;
}

// ---------------------------------------------------------------------------
// gemm256: C = A @ B^T + bias (bf16 out).  256x256 tile, BK=64, 512 threads
// (8 waves 2Mx4N, each wave owns 128x64), double-buffered 128 KiB LDS,
// 4 phases per K-tile, counted vmcnt(6) at K-tile boundaries (T3+T4),
// setprio around MFMA clusters (T5), XOR (r&7) 16B-slot swizzle (T2) applied
// via pre-swizzled global source (gload_lds dest must stay linear).
//
// Staging stream: half-tile h issued at global phase p = h - 7.
//   h%4: 0->B0 (rows 0-127 of B tile), 1->B1, 2->A0, 3->A1.
//   During K-tile kt (phases 4kt..4kt+3) we stage:
//     phi0: A1(kt+1)  [non-live buffer]
//     phi1: B0(kt+2)  [live buffer; B last ds_read drained in phi0 -> safe]
//     phi2: B1(kt+2)  [safe, B last read phi0]
//     phi3: A0(kt+2)  [A last ds_read drained in phi2 -> safe]
//   Boundary entering kt+1: issued through h=4kt+10 -> vmcnt(6) (= 3 stages
//   x 2 loads in flight) leaves exactly the kt+2 half-tiles outstanding; all
//   of kt+1 has landed.
//
// N need not divide 256: B-rows past Nvalid read mapped workspace garbage
// (per-column dot products keep it out of valid columns); stores masked.
// ---------------------------------------------------------------------------
__global__ __launch_bounds__(512, 2) void gemm256_bt_bias(
    const ushort_t* __restrict__ A, const ushort_t* __restrict__ B,
    const float* __restrict__ bias, ushort_t* __restrict__ C,
    int K, int Npitch, int Nvalid)
{
    __shared__ short Sm[65536];   // 128 KiB: buf{0,1} x [A 256x64 | B 256x64]

    const int t = threadIdx.x;
    const int lane = t & 63, w = t >> 6;
    const int qd = lane >> 4, ln = lane & 15;
    const int wm = w >> 2, wn = w & 3;

    // XCD-aware bijective swizzle (448 blocks, 448 % 8 == 0)
    const int nwgx = gridDim.x;
    const int bid = blockIdx.y * nwgx + blockIdx.x;
    const int q8 = (nwgx * gridDim.y) >> 3;
    const int swz = (bid & 7) * q8 + (bid >> 3);
    const int m0 = (swz / nwgx) * 256, n0 = (swz % nwgx) * 256;

    const int NT = K >> 6;   // number of 64-wide K-tiles
    const int H4 = K >> 4;   // total half-tiles (4 per K-tile)

    // ---- staging addresses: slot s=t -> (r=s>>3, c16=s&7); source column
    // pre-swizzled by ^(r&7) so linear LDS holds the swizzled layout ----
    const int sr = t >> 3, sc = t & 7;
    const int csw = (sc ^ (sr & 7)) * 8;
    const ushort_t* pA = A + (size_t)(m0 + sr) * K + csw;
    const ushort_t* pB = B + (size_t)(n0 + sr) * K + csw;
    const size_t rowK64 = (size_t)64 * K;
    const size_t rowK128 = (size_t)128 * K;

    auto stage = [&](int h) {
        if (h >= H4) return;
        const int ktt = h >> 2, reg = h & 3;
        const ushort_t* s0;
        int lo;
        if (reg == 0)      { s0 = pB;           lo = 16384; }
        else if (reg == 1) { s0 = pB + rowK128; lo = 24576; }
        else if (reg == 2) { s0 = pA;           lo = 0;     }
        else               { s0 = pA + rowK128; lo = 8192;  }
        short* d = &Sm[(ktt & 1) * 32768 + lo + t * 8];
        const ushort_t* g = s0 + (size_t)ktt * 64;
        gload_lds16(g, d);                       // rows 0..63 of half-tile
        gload_lds16(g + rowK64, d + 4096);       // rows 64..127
    };

    f32x4 acc[8][4];
#pragma unroll
    for (int i = 0; i < 8; i++)
#pragma unroll
        for (int j = 0; j < 4; j++) acc[i][j] = (f32x4){0.f, 0.f, 0.f, 0.f};

    // reader swizzled 16B-slot offsets (row&7 == ln&7 for all frag rows)
    const int pc0 = (qd ^ (ln & 7)) * 8;
    const int pc1 = ((4 + qd) ^ (ln & 7)) * 8;
    const int arow = wm * 128 + ln;
    const int brow = wn * 64 + ln;

    // ---- prologue: half-tiles 0..6 (kt0 complete + B0,B1,A0 of kt1) ----
#pragma unroll
    for (int h = 0; h < 7; h++) stage(h);
    asm volatile("s_waitcnt vmcnt(6)" ::: "memory");
    __builtin_amdgcn_s_barrier();

    for (int kt = 0; kt < NT; kt++) {
        const int buf = (kt & 1) * 32768;
        const short* Ab = &Sm[buf];
        const short* Bb = &Sm[buf + 16384];
        const int p = kt * 4;

        bf16x8 a[8], bk0[4], bk1[4];

        // ---------------- phase 0: loads A(kk0), B(kk0,kk1); stage A1(kt+1)
#pragma unroll
        for (int mf = 0; mf < 8; mf++)
            a[mf] = *(const bf16x8*)&Ab[(arow + mf * 16) * 64 + pc0];
#pragma unroll
        for (int nf = 0; nf < 4; nf++) {
            bk0[nf] = *(const bf16x8*)&Bb[(brow + nf * 16) * 64 + pc0];
            bk1[nf] = *(const bf16x8*)&Bb[(brow + nf * 16) * 64 + pc1];
        }
        stage(p + 7);
        __builtin_amdgcn_s_barrier();
        asm volatile("s_waitcnt lgkmcnt(0)" ::: "memory");
        __builtin_amdgcn_s_setprio(1);
#pragma unroll
        for (int mf = 0; mf < 8; mf++) {
            acc[mf][0] = __builtin_amdgcn_mfma_f32_16x16x32_bf16(a[mf], bk0[0], acc[mf][0], 0, 0, 0);
            acc[mf][1] = __builtin_amdgcn_mfma_f32_16x16x32_bf16(a[mf], bk0[1], acc[mf][1], 0, 0, 0);
        }
        __builtin_amdgcn_s_setprio(0);
        __builtin_amdgcn_s_barrier();

        // ---------------- phase 1: stage B0(kt+2)
        stage(p + 8);
        __builtin_amdgcn_s_barrier();
        asm volatile("s_waitcnt lgkmcnt(0)" ::: "memory");
        __builtin_amdgcn_s_setprio(1);
#pragma unroll
        for (int mf = 0; mf < 8; mf++) {
            acc[mf][2] = __builtin_amdgcn_mfma_f32_16x16x32_bf16(a[mf], bk0[2], acc[mf][2], 0, 0, 0);
            acc[mf][3] = __builtin_amdgcn_mfma_f32_16x16x32_bf16(a[mf], bk0[3], acc[mf][3], 0, 0, 0);
        }
        __builtin_amdgcn_s_setprio(0);
        __builtin_amdgcn_s_barrier();

        // ---------------- phase 2: loads A(kk1); stage B1(kt+2)
#pragma unroll
        for (int mf = 0; mf < 8; mf++)
            a[mf] = *(const bf16x8*)&Ab[(arow + mf * 16) * 64 + pc1];
        stage(p + 9);
        __builtin_amdgcn_s_barrier();
        asm volatile("s_waitcnt lgkmcnt(0)" ::: "memory");
        __builtin_amdgcn_s_setprio(1);
#pragma unroll
        for (int mf = 0; mf < 8; mf++) {
            acc[mf][0] = __builtin_amdgcn_mfma_f32_16x16x32_bf16(a[mf], bk1[0], acc[mf][0], 0, 0, 0);
            acc[mf][1] = __builtin_amdgcn_mfma_f32_16x16x32_bf16(a[mf], bk1[1], acc[mf][1], 0, 0, 0);
        }
        __builtin_amdgcn_s_setprio(0);
        __builtin_amdgcn_s_barrier();

        // ---------------- phase 3: stage A0(kt+2); counted vmcnt at boundary
        stage(p + 10);
        __builtin_amdgcn_s_barrier();
        asm volatile("s_waitcnt lgkmcnt(0)" ::: "memory");
        __builtin_amdgcn_s_setprio(1);
#pragma unroll
        for (int mf = 0; mf < 8; mf++) {
            acc[mf][2] = __builtin_amdgcn_mfma_f32_16x16x32_bf16(a[mf], bk1[2], acc[mf][2], 0, 0, 0);
            acc[mf][3] = __builtin_amdgcn_mfma_f32_16x16x32_bf16(a[mf], bk1[3], acc[mf][3], 0, 0, 0);
        }
        __builtin_amdgcn_s_setprio(0);
        if (kt < NT - 2) { asm volatile("s_waitcnt vmcnt(6)" ::: "memory"); }
        else             { asm volatile("s_waitcnt vmcnt(0)" ::: "memory"); }
        __builtin_amdgcn_s_barrier();
    }

    // ---- epilogue: bias add, stage C tile in LDS (swizzled), 16B stores ----
    __syncthreads();
    float bv[4];
#pragma unroll
    for (int nf = 0; nf < 4; nf++) {
        const int gc = n0 + wn * 64 + nf * 16 + ln;
        bv[nf] = (gc < Nvalid) ? bias[gc] : 0.f;
    }
    char* Smb = (char*)Sm;
#pragma unroll
    for (int mf = 0; mf < 8; mf++) {
        const int row = wm * 128 + mf * 16 + qd * 4;
#pragma unroll
        for (int nf = 0; nf < 4; nf++) {
            const int swc = ((wn * 64 + nf * 16 + ln) * 2) ^ (qd << 5);
#pragma unroll
            for (int r = 0; r < 4; r++)
                *(ushort_t*)(Smb + (row + r) * 512 + swc) = f2b(acc[mf][nf][r] + bv[nf]);
        }
    }
    __syncthreads();
#pragma unroll
    for (int q = 0; q < 16; q++) {
        const int s = t + q * 512;
        const int row = s >> 5, c8 = s & 31;
        const int gcol = n0 + c8 * 8;
        if (gcol < Nvalid)
            *(us8*)&C[(size_t)(m0 + row) * Npitch + gcol] =
                *(const us8*)(Smb + row * 512 + ((c8 * 16) ^ (((row >> 2) & 3) << 5)));
    }
}

// ---------------------------------------------------------------------------
// C = A @ B^T + bias.  128x128 tile, BK=32, single-barrier async K-loop,
// double-buffered LDS.  (Retained for the f32-output proj GEMM, N=1152.)
// ---------------------------------------------------------------------------
template <bool OUT_F32>
__global__ __launch_bounds__(256, 4) void gemm_bt_bias(
    const ushort_t* __restrict__ A, const ushort_t* __restrict__ B,
    const float* __restrict__ bias, void* __restrict__ Cv,
    int M, int N, int K)
{
    __shared__ short Sm[16384];   // 32 KB: As0|As1|Bs0|Bs1 (4KB shorts each)

    const int t = threadIdx.x;
    const int lane = t & 63, w = t >> 6;
    const int qd = lane >> 4, ln = lane & 15;
    const int wm = w >> 1, wn = w & 1;
    const int m0 = blockIdx.y * 128, n0 = blockIdx.x * 128;
    const int KITER = K >> 5;

    f32x4 acc[4][4];
#pragma unroll
    for (int i = 0; i < 4; i++)
#pragma unroll
        for (int j = 0; j < 4; j++) acc[i][j] = (f32x4){0.f, 0.f, 0.f, 0.f};

    const int rA = t >> 2;
    const int colSw = ((t & 3) ^ ((rA >> 1) & 3)) * 8;
    const ushort_t* gA  = A + (size_t)(m0 + rA) * K + colSw;
    const ushort_t* gA2 = A + (size_t)(m0 + 64 + rA) * K + colSw;
    const ushort_t* gB  = B + (size_t)(n0 + rA) * K + colSw;
    const ushort_t* gB2 = B + (size_t)(n0 + 64 + rA) * K + colSw;

    // prologue: DMA tile 0 into buffer 0 (As0 @0, Bs0 @8192)
    gload_lds16(gA,  Sm + t * 8);
    gload_lds16(gA2, Sm + (t + 256) * 8);
    gload_lds16(gB,  Sm + 8192 + t * 8);
    gload_lds16(gB2, Sm + 8192 + (t + 256) * 8);

    const int pc = (qd ^ ((ln >> 1) & 3)) * 8;   // reader's physical chunk

    for (int kt = 0; kt < KITER; kt++) {
        __syncthreads();                  // drains DMA issued last iter
        if (kt + 1 < KITER) {
            const int k1 = (kt + 1) << 5;
            const int nbo = ((kt + 1) & 1) * 4096;
            gload_lds16(gA + k1,  Sm + nbo + t * 8);
            gload_lds16(gA2 + k1, Sm + nbo + (t + 256) * 8);
            gload_lds16(gB + k1,  Sm + 8192 + nbo + t * 8);
            gload_lds16(gB2 + k1, Sm + 8192 + nbo + (t + 256) * 8);
        }
        const int cbo = (kt & 1) * 4096;
        const short* AsB = Sm + cbo;
        const short* BsB = Sm + 8192 + cbo;

        bf16x8 af[4], bfv[4];
#pragma unroll
        for (int i = 0; i < 4; i++)
            af[i] = *(const bf16x8*)&AsB[(wm * 64 + i * 16 + ln) * 32 + pc];
#pragma unroll
        for (int j = 0; j < 4; j++)
            bfv[j] = *(const bf16x8*)&BsB[(wn * 64 + j * 16 + ln) * 32 + pc];
#pragma unroll
        for (int i = 0; i < 4; i++)
#pragma unroll
            for (int j = 0; j < 4; j++)
                acc[i][j] = __builtin_amdgcn_mfma_f32_16x16x32_bf16(
                    af[i], bfv[j], acc[i][j], 0, 0, 0);
    }

    // ---- epilogue: stage C through LDS, store full 16B lines ----
    float bv[4];
#pragma unroll
    for (int j = 0; j < 4; j++) bv[j] = bias[n0 + wn * 64 + j * 16 + ln];

    if (!OUT_F32) {
        __syncthreads();
        ushort_t* Ct = (ushort_t*)Cv;
#pragma unroll
        for (int i = 0; i < 4; i++)
#pragma unroll
            for (int j = 0; j < 4; j++)
#pragma unroll
                for (int r = 0; r < 4; r++)
                    Sm[(wm * 64 + i * 16 + qd * 4 + r) * 128 + wn * 64 + j * 16 + ln] =
                        (short)f2b(acc[i][j][r] + bv[j]);
        __syncthreads();
#pragma unroll
        for (int q = 0; q < 8; q++) {
            const int c = t + q * 256;
            const int row = c >> 4, cc = c & 15;
            *(us8*)&Ct[(size_t)(m0 + row) * N + n0 + cc * 8] =
                *(const us8*)&Sm[row * 128 + cc * 8];
        }
    } else {
        float* Ct = (float*)Cv;
        float* Cf = (float*)Sm;
#pragma unroll
        for (int p = 0; p < 2; p++) {
            __syncthreads();
            if (wm == p) {
#pragma unroll
                for (int i = 0; i < 4; i++)
#pragma unroll
                    for (int j = 0; j < 4; j++)
#pragma unroll
                        for (int r = 0; r < 4; r++)
                            Cf[(i * 16 + qd * 4 + r) * 128 + wn * 64 + j * 16 + ln] =
                                acc[i][j][r] + bv[j];
            }
            __syncthreads();
#pragma unroll
            for (int q = 0; q < 8; q++) {
                const int c = t + q * 256;
                const int row = c >> 5, cc = c & 31;
                *(f32x4*)&Ct[(size_t)(m0 + p * 64 + row) * N + n0 + cc * 4] =
                    *(const f32x4*)&Cf[row * 128 + cc * 4];
            }
        }
    }
}

// ---------------------------------------------------------------------------
// RoPE.  Q: in-place in qkv[s][0..1151].  K: -> k_buf [128 nh][1024 l][128]
// (cols 72..127 zero; power-of-2 row pitch for swizzled DMA).
// ---------------------------------------------------------------------------
__global__ void rope_qk(ushort_t* __restrict__ qkv,
                        const float* __restrict__ cosb,
                        const float* __restrict__ sinb,
                        ushort_t* __restrict__ kb)
{
    const int idx = blockIdx.x * 256 + threadIdx.x;   // < 8192*144
    const int d0c = idx % 9;
    const int h = (idx / 9) & 15;
    const int s = idx / 144;
    const int d0 = d0c * 4;
    const int n = s >> 10, l = s & 1023;
    const size_t src = (size_t)s * 3456 + h * 72;
    const size_t dstrow = ((size_t)(n * 16 + h) * 1024 + l) * 128;

    f32x4 c1 = *(const f32x4*)&cosb[s * 72 + d0];
    f32x4 c2 = *(const f32x4*)&cosb[s * 72 + d0 + 36];
    f32x4 s1 = *(const f32x4*)&sinb[s * 72 + d0];
    f32x4 s2 = *(const f32x4*)&sinb[s * 72 + d0 + 36];

    {   // Q (in place)
        us4 x1 = *(const us4*)&qkv[src + d0];
        us4 x2 = *(const us4*)&qkv[src + d0 + 36];
        us4 o1, o2;
#pragma unroll
        for (int j = 0; j < 4; j++) {
            float a = b2f(x1[j]), b = b2f(x2[j]);
            o1[j] = f2b(a * c1[j] - b * s1[j]);
            o2[j] = f2b(b * c2[j] + a * s2[j]);
        }
        *(us4*)&qkv[src + d0] = o1;
        *(us4*)&qkv[src + d0 + 36] = o2;
    }
    {   // K -> padded k_buf
        us4 x1 = *(const us4*)&qkv[src + 1152 + d0];
        us4 x2 = *(const us4*)&qkv[src + 1152 + d0 + 36];
        us4 o1, o2;
#pragma unroll
        for (int j = 0; j < 4; j++) {
            float a = b2f(x1[j]), b = b2f(x2[j]);
            o1[j] = f2b(a * c1[j] - b * s1[j]);
            o2[j] = f2b(b * c2[j] + a * s2[j]);
        }
        *(us4*)&kb[dstrow + d0] = o1;
        *(us4*)&kb[dstrow + d0 + 36] = o2;
    }
    if (d0c < 7) {   // zero pad cols 72..127 (7 x us8)
        us8 z = (us8){0, 0, 0, 0, 0, 0, 0, 0};
        *(us8*)&kb[dstrow + 72 + d0c * 8] = z;
    }
}

// ---------------------------------------------------------------------------
// V transpose: qkv(bf16)[s][2304+h*72+d] -> Vt [128 nh][80 d][1024 kv]
// (rows d=72..79 zero).  One block per (nh, 64-kv tile), LDS transpose.
// ---------------------------------------------------------------------------
__global__ void v_transpose(const ushort_t* __restrict__ qkv, ushort_t* __restrict__ vt)
{
    __shared__ short T[64 * 80];
    const int t = threadIdx.x;
    const int nh = blockIdx.x >> 4, kvb = blockIdx.x & 15;
    const int h = nh & 15, n = nh >> 4;
    const int s0 = n * 1024 + kvb * 64;

#pragma unroll
    for (int i = 0; i < 3; i++) {
        int c = t + i * 256;
        if (c < 576) {
            int row = c / 9, off = (c % 9) * 8;
            *(us8*)&T[row * 80 + off] =
                *(const us8*)&qkv[(size_t)(s0 + row) * 3456 + 2304 + h * 72 + off];
        }
    }
    __syncthreads();

#pragma unroll
    for (int i = 0; i < 3; i++) {
        int c = t + i * 256;
        if (c < 640) {
            int d = c >> 3, kc = c & 7;
            us8 o;
            if (d < 72) {
#pragma unroll
                for (int j = 0; j < 8; j++) o[j] = (ushort_t)T[(kc * 8 + j) * 80 + d];
            } else {
                o = (us8){0, 0, 0, 0, 0, 0, 0, 0};
            }
            *(us8*)&vt[((size_t)nh * 80 + d) * 1024 + kvb * 64 + kc * 8] = o;
        }
    }
}

// ---------------------------------------------------------------------------
// Flash attention v2: block = (nh, 256-q tile), 4 waves x 64 q-rows each.
// BKV=32 (one MFMA K-pass for PV).  Static softmax, per-lane partial
// row-sums, epilogue reduction.  K/V double-buffered via XOR-swizzled
// global_load_lds DMA; Ps pitch 40.
// ---------------------------------------------------------------------------
__global__ __launch_bounds__(256, 2) void flash_attn(
    const ushort_t* __restrict__ qkv, const ushort_t* __restrict__ kb,
    const ushort_t* __restrict__ vt, ushort_t* __restrict__ ob)
{
    __shared__ short Ks[2][32 * 128];   // 16384 B  row pitch 256 B
    __shared__ short VtS[2][80 * 32];   // 10240 B  row pitch 64 B
    __shared__ short Ps[4][64 * 40];    // 20480 B  -> total 47104 B

    const int t = threadIdx.x;
    const int lane = t & 63, w = t >> 6;
    const int qd = lane >> 4, ln = lane & 15;
    const int lnx = ln & 7;
    const int lns = (ln >> 1) & 3;
    const int nh = blockIdx.x >> 2, qt = blockIdx.x & 3;
    const int q0 = qt * 256;
    const int h = nh & 15, n = nh >> 4;
    const float scale = 0.11785113019775793f;   // 72^-0.5

    const ushort_t* kbase = kb + (size_t)nh * 1024 * 128;
    const ushort_t* vbase = vt + (size_t)nh * 80 * 1024;

    // ---- Q fragments -> registers.  Wave w owns q rows q0+w*64 .. +63 ----
    bf16x8 qf[4][3];
    {
        const ushort_t* qsrc = qkv + (size_t)(n * 1024 + q0 + w * 64) * 3456 + h * 72;
#pragma unroll
        for (int im = 0; im < 4; im++)
#pragma unroll
            for (int ks = 0; ks < 3; ks++)
                qf[im][ks] = *(const bf16x8*)&qsrc[(size_t)(im * 16 + ln) * 3456 + ks * 32 + qd * 8];
    }

    // ---- prologue: swizzled DMA of kv-tile 0 into buffer 0 ----
#pragma unroll
    for (int i = 0; i < 2; i++) {      // K: 512 chunks (32 rows x 16)
        int c = t + i * 256, r = c >> 4, kc = c & 15;
        gload_lds16(kbase + (size_t)r * 128 + (kc ^ (r & 7)) * 8, &Ks[0][c * 8]);
    }
    {                                   // V: 320 chunks (80 rows x 4)
        int c = t, d = c >> 2, kc = c & 3;
        gload_lds16(vbase + (size_t)d * 1024 + (kc ^ ((d >> 1) & 3)) * 8, &VtS[0][c * 8]);
        if (t < 64) {
            int c2 = t + 256, d2 = c2 >> 2, kc2 = c2 & 3;
            gload_lds16(vbase + (size_t)d2 * 1024 + (kc2 ^ ((d2 >> 1) & 3)) * 8, &VtS[0][c2 * 8]);
        }
    }

    float l_lane[4][4];
    f32x4 acc_o[4][5];
#pragma unroll
    for (int im = 0; im < 4; im++) {
#pragma unroll
        for (int r = 0; r < 4; r++) l_lane[im][r] = 0.f;
#pragma unroll
        for (int jn = 0; jn < 5; jn++) acc_o[im][jn] = (f32x4){0.f, 0.f, 0.f, 0.f};
    }

    for (int it = 0; it < 32; it++) {
        __syncthreads();   // drains DMAs issued last iter; buf^1 free

        if (it < 31) {     // swizzled DMA for kv-tile it+1
            const int nb = (it + 1) & 1;
            const ushort_t* knext = kbase + (size_t)(it + 1) * 4096;
#pragma unroll
            for (int i = 0; i < 2; i++) {
                int c = t + i * 256, r = c >> 4, kc = c & 15;
                gload_lds16(knext + (size_t)r * 128 + (kc ^ (r & 7)) * 8, &Ks[nb][c * 8]);
            }
            const ushort_t* vnext = vbase + (it + 1) * 32;
            {
                int c = t, d = c >> 2, kc = c & 3;
                gload_lds16(vnext + (size_t)d * 1024 + (kc ^ ((d >> 1) & 3)) * 8, &VtS[nb][c * 8]);
                if (t < 64) {
                    int c2 = t + 256, d2 = c2 >> 2, kc2 = c2 & 3;
                    gload_lds16(vnext + (size_t)d2 * 1024 + (kc2 ^ ((d2 >> 1) & 3)) * 8, &VtS[nb][c2 * 8]);
                }
            }
        }

        const short* KsB = Ks[it & 1];
        const short* VtB = VtS[it & 1];

        // ---- Q K^T ----  24 MFMA (4 im x 2 jk x 3 ks)
        f32x4 sc[4][2];
#pragma unroll
        for (int im = 0; im < 4; im++)
#pragma unroll
            for (int jk = 0; jk < 2; jk++) sc[im][jk] = (f32x4){0.f, 0.f, 0.f, 0.f};
#pragma unroll
        for (int ks = 0; ks < 3; ks++) {
            const int m = ks * 4 + qd;
#pragma unroll
            for (int jk = 0; jk < 2; jk++) {
                bf16x8 bfr = *(const bf16x8*)&KsB[(jk * 16 + ln) * 128 + (m ^ lnx) * 8];
#pragma unroll
                for (int im = 0; im < 4; im++)
                    sc[im][jk] = __builtin_amdgcn_mfma_f32_16x16x32_bf16(
                        qf[im][ks], bfr, sc[im][jk], 0, 0, 0);
            }
        }

        // ---- static softmax: p = exp(s*scale), per-lane l partials ----
#pragma unroll
        for (int im = 0; im < 4; im++) {
#pragma unroll
            for (int r = 0; r < 4; r++) {
                float p0 = __expf(sc[im][0][r] * scale);
                float p1 = __expf(sc[im][1][r] * scale);
                l_lane[im][r] += p0 + p1;
                short* pd = &Ps[w][(im * 16 + qd * 4 + r) * 40 + ln];
                pd[0]  = (short)f2b(p0);
                pd[16] = (short)f2b(p1);
            }
        }

        // ---- P V ----  20 MFMA (4 im x 5 jn), single K=32 pass
#pragma unroll
        for (int jn = 0; jn < 5; jn++) {
            bf16x8 vf = *(const bf16x8*)&VtB[(jn * 16 + ln) * 32 + (qd ^ lns) * 8];
#pragma unroll
            for (int im = 0; im < 4; im++) {
                bf16x8 pf = *(const bf16x8*)&Ps[w][(im * 16 + ln) * 40 + qd * 8];
                acc_o[im][jn] = __builtin_amdgcn_mfma_f32_16x16x32_bf16(
                    pf, vf, acc_o[im][jn], 0, 0, 0);
            }
        }
    }

    // ---- epilogue: reduce l across the 16-lane group, normalize, store ----
    const size_t obase = ((size_t)(n * 1024 + q0 + w * 64)) * 1152 + h * 72;
#pragma unroll
    for (int im = 0; im < 4; im++) {
#pragma unroll
        for (int r = 0; r < 4; r++) {
            float l = l_lane[im][r];
            l += __shfl_xor(l, 1);
            l += __shfl_xor(l, 2);
            l += __shfl_xor(l, 4);
            l += __shfl_xor(l, 8);
            const float inv = 1.0f / l;
            const int rowl = im * 16 + qd * 4 + r;
#pragma unroll
            for (int jn = 0; jn < 5; jn++) {
                const int d = jn * 16 + ln;
                if (d < 72)
                    ob[obase + (size_t)rowl * 1152 + d] = f2b(acc_o[im][jn][r] * inv);
            }
        }
    }
}

// ---------------------------------------------------------------------------
extern "C" void kernel_launch(void* const* d_in, const int* in_sizes, int n_in,
                              void* d_out, int out_size, void* d_ws, size_t ws_size,
                              hipStream_t stream)
{
    const float* hs     = (const float*)d_in[0];
    const float* cosb   = (const float*)d_in[1];
    const float* sinb   = (const float*)d_in[2];
    const float* qkv_w  = (const float*)d_in[3];
    const float* qkv_b  = (const float*)d_in[4];
    const float* proj_w = (const float*)d_in[5];
    const float* proj_b = (const float*)d_in[6];

    char* ws = (char*)d_ws;
    // hidden_bf16 (dead after gemm1) aliases attn (written by flash_attn)
    ushort_t* hs_bf   = (ushort_t*)(ws);                //  8192*1152*2 = 18,874,368
    ushort_t* attn    = (ushort_t*)(ws);                //  aliases hs_bf
    ushort_t* qkvw_bf = (ushort_t*)(ws + 18874368);     //  3456*1152*2 =  7,962,624
    ushort_t* projw_bf= (ushort_t*)(ws + 26836992);     //  1152*1152*2 =  2,654,208
    ushort_t* qkv_tmp = (ushort_t*)(ws + 29491200);     //  8192*3456*2 = 56,623,104
    ushort_t* k_buf   = (ushort_t*)(ws + 86114304);     //  128*1024*128*2 = 33,554,432
    ushort_t* v_t     = (ushort_t*)(ws + 119668736);    //  128*80*1024*2  = 20,971,520
    float*    out     = (float*)d_out;                  //  total ws: 140,640,256 B

    cvt_f32_bf16<<<4608, 256, 0, stream>>>(hs, hs_bf, 9437184 / 8);
    cvt_f32_bf16<<<1944, 256, 0, stream>>>(qkv_w, qkvw_bf, 3981312 / 8);
    cvt_f32_bf16<<<648, 256, 0, stream>>>(proj_w, projw_bf, 1327104 / 8);

    // QKV GEMM: M=8192, N=3456 (14 x 256 tiles, last tile masked), K=1152
    gemm256_bt_bias<<<dim3(14, 32), 512, 0, stream>>>(hs_bf, qkvw_bf, qkv_b, qkv_tmp, 1152, 3456, 3456);
    rope_qk<<<4608, 256, 0, stream>>>(qkv_tmp, cosb, sinb, k_buf);
    v_transpose<<<2048, 256, 0, stream>>>(qkv_tmp, v_t);
    flash_attn<<<512, 256, 0, stream>>>(qkv_tmp, k_buf, v_t, attn);
    gemm_bt_bias<true><<<dim3(9, 64), 256, 0, stream>>>(attn, projw_bf, proj_b, out, 8192, 1152, 1152);
}

// Round 3
// 333.311 us; speedup vs baseline: 1.0648x; 1.0176x over previous
//
#include <hip/hip_runtime.h>
#include <stdint.h>

typedef unsigned short ushort_t;
typedef short bf16x8 __attribute__((ext_vector_type(8)));
typedef float f32x4 __attribute__((ext_vector_type(4)));
typedef ushort_t us2 __attribute__((ext_vector_type(2)));
typedef ushort_t us4 __attribute__((ext_vector_type(4)));
typedef ushort_t us8 __attribute__((ext_vector_type(8)));

__device__ __forceinline__ float b2f(ushort_t u) {
    union { unsigned int i; float f; } v; v.i = ((unsigned int)u) << 16; return v.f;
}
__device__ __forceinline__ ushort_t f2b(float f) {
    union { float f; unsigned int i; } v; v.f = f;
    unsigned int r = v.i + 0x7fffu + ((v.i >> 16) & 1u);
    return (ushort_t)(r >> 16);
}

typedef __attribute__((address_space(3))) unsigned int lds_u32;
typedef __attribute__((address_space(1))) const unsigned int gbl_u32;

__device__ __forceinline__ void gload_lds16(const void* g, void* l) {
    __builtin_amdgcn_global_load_lds((gbl_u32*)g, (lds_u32*)l, 16, 0, 0);
}

// ---------------------------------------------------------------------------
// fp32 -> bf16 elementwise convert, 8 elems/thread.
// ---------------------------------------------------------------------------
__global__ void cvt_f32_bf16(const float* __restrict__ src, ushort_t* __restrict__ dst, int n8)
{
    const int i = blockIdx.x * 256 + threadIdx.x;
    if (i >= n8) return;
    f32x4 a = *(const f32x4*)&src[i * 8];
    f32x4 b = *(const f32x4*)&src[i * 8 + 4];
    us8 o;
#pragma unroll
    for (int j = 0; j < 4; j++) { o[j] = f2b(a[j]); o[j + 4] = f2b(b[j]); }
    *(us8*)&dst[i * 8] = o;
}

// ---------------------------------------------------------------------------
// gemm256 v2: C = A @ B^T + bias (bf16 out).  256x256 tile, BK=64, 512 thr
// (8 waves 2Mx4N, per-wave 128x64), double-buffered 128 KiB LDS.
// 4 phases/K-tile, ONE barrier per phase (waves slip within a phase ->
// ds_read/MFMA overlap across waves), even-ish read distribution 10/6/8/0,
// counted vmcnt(4) at K-tile boundaries, setprio around MFMA, XOR (r&7)
// 16B-slot swizzle via pre-swizzled global source.
//
// Staging: half-tile h issued at phase h-6.  h%4: 0->B0, 1->B1, 2->A0, 3->A1.
// During kt: ph0 -> A0(kt+1) [non-live buf], ph1 -> A1(kt+1) [non-live],
//            ph2 -> B0(kt+2) [live-B rows 0-127; B reads confined to ph0-1,
//                   drained at ph1 end-barrier -> safe],
//            ph3 -> B1(kt+2) [live-B rows 128-255; same argument].
// A-stages target the non-live buffer (last A-read was kt-1 ph2 -> safe).
// Phase fence: asm lgkmcnt(0)+"memory" before each barrier pins each phase's
// read set (compiler can't move ds_reads across) and guarantees WAR drain.
// Boundary entering kt+1: issued <= h=4kt+9; kt+1 complete at h=4kt+7 ->
// vmcnt(4) leaves exactly {B0,B1}(kt+2) in flight.  vmcnt(0) for the last
// two kt (no kt+2 stages exist -> 4-deep count would strand kt+1 loads).
//
// Reads per phase: ph0: a0[8]+bk0[0,1]; ph1: bk0[2,3]+bk1[0..3]; ph2: a1[8];
// ph3: none.  MFMA per phase: 16 (a0xbk0[0,1] / a0xbk0[2,3] / a1xbk1[0,1] /
// a1xbk1[2,3]).
//
// N need not divide 256: B-rows past Nvalid read mapped workspace garbage
// (per-column dot products keep it out of valid columns); stores masked.
// ---------------------------------------------------------------------------
__global__ __launch_bounds__(512, 2) void gemm256_bt_bias(
    const ushort_t* __restrict__ A, const ushort_t* __restrict__ B,
    const float* __restrict__ bias, ushort_t* __restrict__ C,
    int K, int Npitch, int Nvalid)
{
    __shared__ short Sm[65536];   // 128 KiB: buf{0,1} x [A 256x64 | B 256x64]

    const int t = threadIdx.x;
    const int lane = t & 63, w = t >> 6;
    const int qd = lane >> 4, ln = lane & 15;
    const int wm = w >> 2, wn = w & 3;

    // XCD-aware bijective swizzle (448 blocks, 448 % 8 == 0)
    const int nwgx = gridDim.x;
    const int bid = blockIdx.y * nwgx + blockIdx.x;
    const int q8 = (nwgx * gridDim.y) >> 3;
    const int swz = (bid & 7) * q8 + (bid >> 3);
    const int m0 = (swz / nwgx) * 256, n0 = (swz % nwgx) * 256;

    const int NT = K >> 6;   // number of 64-wide K-tiles
    const int H4 = K >> 4;   // total half-tiles (4 per K-tile)

    // ---- staging addresses: slot s=t -> (r=s>>3, c16=s&7); source column
    // pre-swizzled by ^(r&7) so linear LDS holds the swizzled layout ----
    const int sr = t >> 3, sc = t & 7;
    const int csw = (sc ^ (sr & 7)) * 8;
    const ushort_t* pA = A + (size_t)(m0 + sr) * K + csw;
    const ushort_t* pB = B + (size_t)(n0 + sr) * K + csw;
    const size_t rowK64 = (size_t)64 * K;
    const size_t rowK128 = (size_t)128 * K;

    auto stage = [&](int h) {
        if (h >= H4) return;
        const int ktt = h >> 2, reg = h & 3;
        const ushort_t* s0;
        int lo;
        if (reg == 0)      { s0 = pB;           lo = 16384; }
        else if (reg == 1) { s0 = pB + rowK128; lo = 24576; }
        else if (reg == 2) { s0 = pA;           lo = 0;     }
        else               { s0 = pA + rowK128; lo = 8192;  }
        short* d = &Sm[(ktt & 1) * 32768 + lo + t * 8];
        const ushort_t* g = s0 + (size_t)ktt * 64;
        gload_lds16(g, d);                       // rows 0..63 of half-tile
        gload_lds16(g + rowK64, d + 4096);       // rows 64..127
    };

    f32x4 acc[8][4];
#pragma unroll
    for (int i = 0; i < 8; i++)
#pragma unroll
        for (int j = 0; j < 4; j++) acc[i][j] = (f32x4){0.f, 0.f, 0.f, 0.f};

    // reader swizzled 16B-slot offsets (row&7 == ln&7 for all frag rows)
    const int pc0 = (qd ^ (ln & 7)) * 8;
    const int pc1 = ((4 + qd) ^ (ln & 7)) * 8;
    const int arow = wm * 128 + ln;
    const int brow = wn * 64 + ln;

    // ---- prologue: half-tiles 0..5 (kt0 complete + B0,B1 of kt1) ----
#pragma unroll
    for (int h = 0; h < 6; h++) stage(h);
    asm volatile("s_waitcnt vmcnt(4)" ::: "memory");
    __builtin_amdgcn_s_barrier();

    for (int kt = 0; kt < NT; kt++) {
        const int buf = (kt & 1) * 32768;
        const short* Ab = &Sm[buf];
        const short* Bb = &Sm[buf + 16384];
        const int p = kt * 4;

        bf16x8 a[8], bk0[4], bk1[4];

        // -------- phase 0: reads a0[8]+bk0[0,1]; stage A0(kt+1); MFMA x16
#pragma unroll
        for (int mf = 0; mf < 8; mf++)
            a[mf] = *(const bf16x8*)&Ab[(arow + mf * 16) * 64 + pc0];
        bk0[0] = *(const bf16x8*)&Bb[(brow + 0)  * 64 + pc0];
        bk0[1] = *(const bf16x8*)&Bb[(brow + 16) * 64 + pc0];
        stage(p + 6);
        __builtin_amdgcn_s_setprio(1);
#pragma unroll
        for (int mf = 0; mf < 8; mf++) {
            acc[mf][0] = __builtin_amdgcn_mfma_f32_16x16x32_bf16(a[mf], bk0[0], acc[mf][0], 0, 0, 0);
            acc[mf][1] = __builtin_amdgcn_mfma_f32_16x16x32_bf16(a[mf], bk0[1], acc[mf][1], 0, 0, 0);
        }
        __builtin_amdgcn_s_setprio(0);
        asm volatile("s_waitcnt lgkmcnt(0)" ::: "memory");
        __builtin_amdgcn_s_barrier();

        // -------- phase 1: reads bk0[2,3]+bk1[0..3]; stage A1(kt+1); MFMA x16
        bk0[2] = *(const bf16x8*)&Bb[(brow + 32) * 64 + pc0];
        bk0[3] = *(const bf16x8*)&Bb[(brow + 48) * 64 + pc0];
#pragma unroll
        for (int nf = 0; nf < 4; nf++)
            bk1[nf] = *(const bf16x8*)&Bb[(brow + nf * 16) * 64 + pc1];
        stage(p + 7);
        __builtin_amdgcn_s_setprio(1);
#pragma unroll
        for (int mf = 0; mf < 8; mf++) {
            acc[mf][2] = __builtin_amdgcn_mfma_f32_16x16x32_bf16(a[mf], bk0[2], acc[mf][2], 0, 0, 0);
            acc[mf][3] = __builtin_amdgcn_mfma_f32_16x16x32_bf16(a[mf], bk0[3], acc[mf][3], 0, 0, 0);
        }
        __builtin_amdgcn_s_setprio(0);
        asm volatile("s_waitcnt lgkmcnt(0)" ::: "memory");
        __builtin_amdgcn_s_barrier();

        // -------- phase 2: reads a1[8]; stage B0(kt+2); MFMA x16
#pragma unroll
        for (int mf = 0; mf < 8; mf++)
            a[mf] = *(const bf16x8*)&Ab[(arow + mf * 16) * 64 + pc1];
        stage(p + 8);
        __builtin_amdgcn_s_setprio(1);
#pragma unroll
        for (int mf = 0; mf < 8; mf++) {
            acc[mf][0] = __builtin_amdgcn_mfma_f32_16x16x32_bf16(a[mf], bk1[0], acc[mf][0], 0, 0, 0);
            acc[mf][1] = __builtin_amdgcn_mfma_f32_16x16x32_bf16(a[mf], bk1[1], acc[mf][1], 0, 0, 0);
        }
        __builtin_amdgcn_s_setprio(0);
        asm volatile("s_waitcnt lgkmcnt(0)" ::: "memory");
        __builtin_amdgcn_s_barrier();

        // -------- phase 3: stage B1(kt+2); MFMA x16; counted vmcnt boundary
        stage(p + 9);
        __builtin_amdgcn_s_setprio(1);
#pragma unroll
        for (int mf = 0; mf < 8; mf++) {
            acc[mf][2] = __builtin_amdgcn_mfma_f32_16x16x32_bf16(a[mf], bk1[2], acc[mf][2], 0, 0, 0);
            acc[mf][3] = __builtin_amdgcn_mfma_f32_16x16x32_bf16(a[mf], bk1[3], acc[mf][3], 0, 0, 0);
        }
        __builtin_amdgcn_s_setprio(0);
        asm volatile("s_waitcnt lgkmcnt(0)" ::: "memory");
        if (kt < NT - 2) { asm volatile("s_waitcnt vmcnt(4)" ::: "memory"); }
        else             { asm volatile("s_waitcnt vmcnt(0)" ::: "memory"); }
        __builtin_amdgcn_s_barrier();
    }

    // ---- epilogue: bias add, stage C tile in LDS (swizzled), 16B stores ----
    __syncthreads();
    float bv[4];
#pragma unroll
    for (int nf = 0; nf < 4; nf++) {
        const int gc = n0 + wn * 64 + nf * 16 + ln;
        bv[nf] = (gc < Nvalid) ? bias[gc] : 0.f;
    }
    char* Smb = (char*)Sm;
#pragma unroll
    for (int mf = 0; mf < 8; mf++) {
        const int row = wm * 128 + mf * 16 + qd * 4;
#pragma unroll
        for (int nf = 0; nf < 4; nf++) {
            const int swc = ((wn * 64 + nf * 16 + ln) * 2) ^ (qd << 5);
#pragma unroll
            for (int r = 0; r < 4; r++)
                *(ushort_t*)(Smb + (row + r) * 512 + swc) = f2b(acc[mf][nf][r] + bv[nf]);
        }
    }
    __syncthreads();
#pragma unroll
    for (int q = 0; q < 16; q++) {
        const int s = t + q * 512;
        const int row = s >> 5, c8 = s & 31;
        const int gcol = n0 + c8 * 8;
        if (gcol < Nvalid)
            *(us8*)&C[(size_t)(m0 + row) * Npitch + gcol] =
                *(const us8*)(Smb + row * 512 + ((c8 * 16) ^ (((row >> 2) & 3) << 5)));
    }
}

// ---------------------------------------------------------------------------
// C = A @ B^T + bias.  128x128 tile, BK=32, single-barrier async K-loop,
// double-buffered LDS.  (Retained for the f32-output proj GEMM, N=1152.)
// ---------------------------------------------------------------------------
template <bool OUT_F32>
__global__ __launch_bounds__(256, 4) void gemm_bt_bias(
    const ushort_t* __restrict__ A, const ushort_t* __restrict__ B,
    const float* __restrict__ bias, void* __restrict__ Cv,
    int M, int N, int K)
{
    __shared__ short Sm[16384];   // 32 KB: As0|As1|Bs0|Bs1 (4KB shorts each)

    const int t = threadIdx.x;
    const int lane = t & 63, w = t >> 6;
    const int qd = lane >> 4, ln = lane & 15;
    const int wm = w >> 1, wn = w & 1;
    const int m0 = blockIdx.y * 128, n0 = blockIdx.x * 128;
    const int KITER = K >> 5;

    f32x4 acc[4][4];
#pragma unroll
    for (int i = 0; i < 4; i++)
#pragma unroll
        for (int j = 0; j < 4; j++) acc[i][j] = (f32x4){0.f, 0.f, 0.f, 0.f};

    const int rA = t >> 2;
    const int colSw = ((t & 3) ^ ((rA >> 1) & 3)) * 8;
    const ushort_t* gA  = A + (size_t)(m0 + rA) * K + colSw;
    const ushort_t* gA2 = A + (size_t)(m0 + 64 + rA) * K + colSw;
    const ushort_t* gB  = B + (size_t)(n0 + rA) * K + colSw;
    const ushort_t* gB2 = B + (size_t)(n0 + 64 + rA) * K + colSw;

    // prologue: DMA tile 0 into buffer 0 (As0 @0, Bs0 @8192)
    gload_lds16(gA,  Sm + t * 8);
    gload_lds16(gA2, Sm + (t + 256) * 8);
    gload_lds16(gB,  Sm + 8192 + t * 8);
    gload_lds16(gB2, Sm + 8192 + (t + 256) * 8);

    const int pc = (qd ^ ((ln >> 1) & 3)) * 8;   // reader's physical chunk

    for (int kt = 0; kt < KITER; kt++) {
        __syncthreads();                  // drains DMA issued last iter
        if (kt + 1 < KITER) {
            const int k1 = (kt + 1) << 5;
            const int nbo = ((kt + 1) & 1) * 4096;
            gload_lds16(gA + k1,  Sm + nbo + t * 8);
            gload_lds16(gA2 + k1, Sm + nbo + (t + 256) * 8);
            gload_lds16(gB + k1,  Sm + 8192 + nbo + t * 8);
            gload_lds16(gB2 + k1, Sm + 8192 + nbo + (t + 256) * 8);
        }
        const int cbo = (kt & 1) * 4096;
        const short* AsB = Sm + cbo;
        const short* BsB = Sm + 8192 + cbo;

        bf16x8 af[4], bfv[4];
#pragma unroll
        for (int i = 0; i < 4; i++)
            af[i] = *(const bf16x8*)&AsB[(wm * 64 + i * 16 + ln) * 32 + pc];
#pragma unroll
        for (int j = 0; j < 4; j++)
            bfv[j] = *(const bf16x8*)&BsB[(wn * 64 + j * 16 + ln) * 32 + pc];
#pragma unroll
        for (int i = 0; i < 4; i++)
#pragma unroll
            for (int j = 0; j < 4; j++)
                acc[i][j] = __builtin_amdgcn_mfma_f32_16x16x32_bf16(
                    af[i], bfv[j], acc[i][j], 0, 0, 0);
    }

    // ---- epilogue: stage C through LDS, store full 16B lines ----
    float bv[4];
#pragma unroll
    for (int j = 0; j < 4; j++) bv[j] = bias[n0 + wn * 64 + j * 16 + ln];

    if (!OUT_F32) {
        __syncthreads();
        ushort_t* Ct = (ushort_t*)Cv;
#pragma unroll
        for (int i = 0; i < 4; i++)
#pragma unroll
            for (int j = 0; j < 4; j++)
#pragma unroll
                for (int r = 0; r < 4; r++)
                    Sm[(wm * 64 + i * 16 + qd * 4 + r) * 128 + wn * 64 + j * 16 + ln] =
                        (short)f2b(acc[i][j][r] + bv[j]);
        __syncthreads();
#pragma unroll
        for (int q = 0; q < 8; q++) {
            const int c = t + q * 256;
            const int row = c >> 4, cc = c & 15;
            *(us8*)&Ct[(size_t)(m0 + row) * N + n0 + cc * 8] =
                *(const us8*)&Sm[row * 128 + cc * 8];
        }
    } else {
        float* Ct = (float*)Cv;
        float* Cf = (float*)Sm;
#pragma unroll
        for (int p = 0; p < 2; p++) {
            __syncthreads();
            if (wm == p) {
#pragma unroll
                for (int i = 0; i < 4; i++)
#pragma unroll
                    for (int j = 0; j < 4; j++)
#pragma unroll
                        for (int r = 0; r < 4; r++)
                            Cf[(i * 16 + qd * 4 + r) * 128 + wn * 64 + j * 16 + ln] =
                                acc[i][j][r] + bv[j];
            }
            __syncthreads();
#pragma unroll
            for (int q = 0; q < 8; q++) {
                const int c = t + q * 256;
                const int row = c >> 5, cc = c & 31;
                *(f32x4*)&Ct[(size_t)(m0 + p * 64 + row) * N + n0 + cc * 4] =
                    *(const f32x4*)&Cf[row * 128 + cc * 4];
            }
        }
    }
}

// ---------------------------------------------------------------------------
// RoPE.  Q: in-place in qkv[s][0..1151].  K: -> k_buf [128 nh][1024 l][128]
// (cols 72..127 zero; power-of-2 row pitch for swizzled DMA).
// ---------------------------------------------------------------------------
__global__ void rope_qk(ushort_t* __restrict__ qkv,
                        const float* __restrict__ cosb,
                        const float* __restrict__ sinb,
                        ushort_t* __restrict__ kb)
{
    const int idx = blockIdx.x * 256 + threadIdx.x;   // < 8192*144
    const int d0c = idx % 9;
    const int h = (idx / 9) & 15;
    const int s = idx / 144;
    const int d0 = d0c * 4;
    const int n = s >> 10, l = s & 1023;
    const size_t src = (size_t)s * 3456 + h * 72;
    const size_t dstrow = ((size_t)(n * 16 + h) * 1024 + l) * 128;

    f32x4 c1 = *(const f32x4*)&cosb[s * 72 + d0];
    f32x4 c2 = *(const f32x4*)&cosb[s * 72 + d0 + 36];
    f32x4 s1 = *(const f32x4*)&sinb[s * 72 + d0];
    f32x4 s2 = *(const f32x4*)&sinb[s * 72 + d0 + 36];

    {   // Q (in place)
        us4 x1 = *(const us4*)&qkv[src + d0];
        us4 x2 = *(const us4*)&qkv[src + d0 + 36];
        us4 o1, o2;
#pragma unroll
        for (int j = 0; j < 4; j++) {
            float a = b2f(x1[j]), b = b2f(x2[j]);
            o1[j] = f2b(a * c1[j] - b * s1[j]);
            o2[j] = f2b(b * c2[j] + a * s2[j]);
        }
        *(us4*)&qkv[src + d0] = o1;
        *(us4*)&qkv[src + d0 + 36] = o2;
    }
    {   // K -> padded k_buf
        us4 x1 = *(const us4*)&qkv[src + 1152 + d0];
        us4 x2 = *(const us4*)&qkv[src + 1152 + d0 + 36];
        us4 o1, o2;
#pragma unroll
        for (int j = 0; j < 4; j++) {
            float a = b2f(x1[j]), b = b2f(x2[j]);
            o1[j] = f2b(a * c1[j] - b * s1[j]);
            o2[j] = f2b(b * c2[j] + a * s2[j]);
        }
        *(us4*)&kb[dstrow + d0] = o1;
        *(us4*)&kb[dstrow + d0 + 36] = o2;
    }
    if (d0c < 7) {   // zero pad cols 72..127 (7 x us8)
        us8 z = (us8){0, 0, 0, 0, 0, 0, 0, 0};
        *(us8*)&kb[dstrow + 72 + d0c * 8] = z;
    }
}

// ---------------------------------------------------------------------------
// V transpose: qkv(bf16)[s][2304+h*72+d] -> Vt [128 nh][80 d][1024 kv]
// (rows d=72..79 zero).  One block per (nh, 64-kv tile), LDS transpose.
// ---------------------------------------------------------------------------
__global__ void v_transpose(const ushort_t* __restrict__ qkv, ushort_t* __restrict__ vt)
{
    __shared__ short T[64 * 80];
    const int t = threadIdx.x;
    const int nh = blockIdx.x >> 4, kvb = blockIdx.x & 15;
    const int h = nh & 15, n = nh >> 4;
    const int s0 = n * 1024 + kvb * 64;

#pragma unroll
    for (int i = 0; i < 3; i++) {
        int c = t + i * 256;
        if (c < 576) {
            int row = c / 9, off = (c % 9) * 8;
            *(us8*)&T[row * 80 + off] =
                *(const us8*)&qkv[(size_t)(s0 + row) * 3456 + 2304 + h * 72 + off];
        }
    }
    __syncthreads();

#pragma unroll
    for (int i = 0; i < 3; i++) {
        int c = t + i * 256;
        if (c < 640) {
            int d = c >> 3, kc = c & 7;
            us8 o;
            if (d < 72) {
#pragma unroll
                for (int j = 0; j < 8; j++) o[j] = (ushort_t)T[(kc * 8 + j) * 80 + d];
            } else {
                o = (us8){0, 0, 0, 0, 0, 0, 0, 0};
            }
            *(us8*)&vt[((size_t)nh * 80 + d) * 1024 + kvb * 64 + kc * 8] = o;
        }
    }
}

// ---------------------------------------------------------------------------
// Flash attention v2: block = (nh, 256-q tile), 4 waves x 64 q-rows each.
// BKV=32 (one MFMA K-pass for PV).  Static softmax, per-lane partial
// row-sums, epilogue reduction.  K/V double-buffered via XOR-swizzled
// global_load_lds DMA; Ps pitch 40.
// ---------------------------------------------------------------------------
__global__ __launch_bounds__(256, 2) void flash_attn(
    const ushort_t* __restrict__ qkv, const ushort_t* __restrict__ kb,
    const ushort_t* __restrict__ vt, ushort_t* __restrict__ ob)
{
    __shared__ short Ks[2][32 * 128];   // 16384 B  row pitch 256 B
    __shared__ short VtS[2][80 * 32];   // 10240 B  row pitch 64 B
    __shared__ short Ps[4][64 * 40];    // 20480 B  -> total 47104 B

    const int t = threadIdx.x;
    const int lane = t & 63, w = t >> 6;
    const int qd = lane >> 4, ln = lane & 15;
    const int lnx = ln & 7;
    const int lns = (ln >> 1) & 3;
    const int nh = blockIdx.x >> 2, qt = blockIdx.x & 3;
    const int q0 = qt * 256;
    const int h = nh & 15, n = nh >> 4;
    const float scale = 0.11785113019775793f;   // 72^-0.5

    const ushort_t* kbase = kb + (size_t)nh * 1024 * 128;
    const ushort_t* vbase = vt + (size_t)nh * 80 * 1024;

    // ---- Q fragments -> registers.  Wave w owns q rows q0+w*64 .. +63 ----
    bf16x8 qf[4][3];
    {
        const ushort_t* qsrc = qkv + (size_t)(n * 1024 + q0 + w * 64) * 3456 + h * 72;
#pragma unroll
        for (int im = 0; im < 4; im++)
#pragma unroll
            for (int ks = 0; ks < 3; ks++)
                qf[im][ks] = *(const bf16x8*)&qsrc[(size_t)(im * 16 + ln) * 3456 + ks * 32 + qd * 8];
    }

    // ---- prologue: swizzled DMA of kv-tile 0 into buffer 0 ----
#pragma unroll
    for (int i = 0; i < 2; i++) {      // K: 512 chunks (32 rows x 16)
        int c = t + i * 256, r = c >> 4, kc = c & 15;
        gload_lds16(kbase + (size_t)r * 128 + (kc ^ (r & 7)) * 8, &Ks[0][c * 8]);
    }
    {                                   // V: 320 chunks (80 rows x 4)
        int c = t, d = c >> 2, kc = c & 3;
        gload_lds16(vbase + (size_t)d * 1024 + (kc ^ ((d >> 1) & 3)) * 8, &VtS[0][c * 8]);
        if (t < 64) {
            int c2 = t + 256, d2 = c2 >> 2, kc2 = c2 & 3;
            gload_lds16(vbase + (size_t)d2 * 1024 + (kc2 ^ ((d2 >> 1) & 3)) * 8, &VtS[0][c2 * 8]);
        }
    }

    float l_lane[4][4];
    f32x4 acc_o[4][5];
#pragma unroll
    for (int im = 0; im < 4; im++) {
#pragma unroll
        for (int r = 0; r < 4; r++) l_lane[im][r] = 0.f;
#pragma unroll
        for (int jn = 0; jn < 5; jn++) acc_o[im][jn] = (f32x4){0.f, 0.f, 0.f, 0.f};
    }

    for (int it = 0; it < 32; it++) {
        __syncthreads();   // drains DMAs issued last iter; buf^1 free

        if (it < 31) {     // swizzled DMA for kv-tile it+1
            const int nb = (it + 1) & 1;
            const ushort_t* knext = kbase + (size_t)(it + 1) * 4096;
#pragma unroll
            for (int i = 0; i < 2; i++) {
                int c = t + i * 256, r = c >> 4, kc = c & 15;
                gload_lds16(knext + (size_t)r * 128 + (kc ^ (r & 7)) * 8, &Ks[nb][c * 8]);
            }
            const ushort_t* vnext = vbase + (it + 1) * 32;
            {
                int c = t, d = c >> 2, kc = c & 3;
                gload_lds16(vnext + (size_t)d * 1024 + (kc ^ ((d >> 1) & 3)) * 8, &VtS[nb][c * 8]);
                if (t < 64) {
                    int c2 = t + 256, d2 = c2 >> 2, kc2 = c2 & 3;
                    gload_lds16(vnext + (size_t)d2 * 1024 + (kc2 ^ ((d2 >> 1) & 3)) * 8, &VtS[nb][c2 * 8]);
                }
            }
        }

        const short* KsB = Ks[it & 1];
        const short* VtB = VtS[it & 1];

        // ---- Q K^T ----  24 MFMA (4 im x 2 jk x 3 ks)
        f32x4 sc[4][2];
#pragma unroll
        for (int im = 0; im < 4; im++)
#pragma unroll
            for (int jk = 0; jk < 2; jk++) sc[im][jk] = (f32x4){0.f, 0.f, 0.f, 0.f};
#pragma unroll
        for (int ks = 0; ks < 3; ks++) {
            const int m = ks * 4 + qd;
#pragma unroll
            for (int jk = 0; jk < 2; jk++) {
                bf16x8 bfr = *(const bf16x8*)&KsB[(jk * 16 + ln) * 128 + (m ^ lnx) * 8];
#pragma unroll
                for (int im = 0; im < 4; im++)
                    sc[im][jk] = __builtin_amdgcn_mfma_f32_16x16x32_bf16(
                        qf[im][ks], bfr, sc[im][jk], 0, 0, 0);
            }
        }

        // ---- static softmax: p = exp(s*scale), per-lane l partials ----
#pragma unroll
        for (int im = 0; im < 4; im++) {
#pragma unroll
            for (int r = 0; r < 4; r++) {
                float p0 = __expf(sc[im][0][r] * scale);
                float p1 = __expf(sc[im][1][r] * scale);
                l_lane[im][r] += p0 + p1;
                short* pd = &Ps[w][(im * 16 + qd * 4 + r) * 40 + ln];
                pd[0]  = (short)f2b(p0);
                pd[16] = (short)f2b(p1);
            }
        }

        // ---- P V ----  20 MFMA (4 im x 5 jn), single K=32 pass
#pragma unroll
        for (int jn = 0; jn < 5; jn++) {
            bf16x8 vf = *(const bf16x8*)&VtB[(jn * 16 + ln) * 32 + (qd ^ lns) * 8];
#pragma unroll
            for (int im = 0; im < 4; im++) {
                bf16x8 pf = *(const bf16x8*)&Ps[w][(im * 16 + ln) * 40 + qd * 8];
                acc_o[im][jn] = __builtin_amdgcn_mfma_f32_16x16x32_bf16(
                    pf, vf, acc_o[im][jn], 0, 0, 0);
            }
        }
    }

    // ---- epilogue: reduce l across the 16-lane group, normalize, store ----
    const size_t obase = ((size_t)(n * 1024 + q0 + w * 64)) * 1152 + h * 72;
#pragma unroll
    for (int im = 0; im < 4; im++) {
#pragma unroll
        for (int r = 0; r < 4; r++) {
            float l = l_lane[im][r];
            l += __shfl_xor(l, 1);
            l += __shfl_xor(l, 2);
            l += __shfl_xor(l, 4);
            l += __shfl_xor(l, 8);
            const float inv = 1.0f / l;
            const int rowl = im * 16 + qd * 4 + r;
#pragma unroll
            for (int jn = 0; jn < 5; jn++) {
                const int d = jn * 16 + ln;
                if (d < 72)
                    ob[obase + (size_t)rowl * 1152 + d] = f2b(acc_o[im][jn][r] * inv);
            }
        }
    }
}

// ---------------------------------------------------------------------------
extern "C" void kernel_launch(void* const* d_in, const int* in_sizes, int n_in,
                              void* d_out, int out_size, void* d_ws, size_t ws_size,
                              hipStream_t stream)
{
    const float* hs     = (const float*)d_in[0];
    const float* cosb   = (const float*)d_in[1];
    const float* sinb   = (const float*)d_in[2];
    const float* qkv_w  = (const float*)d_in[3];
    const float* qkv_b  = (const float*)d_in[4];
    const float* proj_w = (const float*)d_in[5];
    const float* proj_b = (const float*)d_in[6];

    char* ws = (char*)d_ws;
    // hidden_bf16 (dead after gemm1) aliases attn (written by flash_attn)
    ushort_t* hs_bf   = (ushort_t*)(ws);                //  8192*1152*2 = 18,874,368
    ushort_t* attn    = (ushort_t*)(ws);                //  aliases hs_bf
    ushort_t* qkvw_bf = (ushort_t*)(ws + 18874368);     //  3456*1152*2 =  7,962,624
    ushort_t* projw_bf= (ushort_t*)(ws + 26836992);     //  1152*1152*2 =  2,654,208
    ushort_t* qkv_tmp = (ushort_t*)(ws + 29491200);     //  8192*3456*2 = 56,623,104
    ushort_t* k_buf   = (ushort_t*)(ws + 86114304);     //  128*1024*128*2 = 33,554,432
    ushort_t* v_t     = (ushort_t*)(ws + 119668736);    //  128*80*1024*2  = 20,971,520
    float*    out     = (float*)d_out;                  //  total ws: 140,640,256 B

    cvt_f32_bf16<<<4608, 256, 0, stream>>>(hs, hs_bf, 9437184 / 8);
    cvt_f32_bf16<<<1944, 256, 0, stream>>>(qkv_w, qkvw_bf, 3981312 / 8);
    cvt_f32_bf16<<<648, 256, 0, stream>>>(proj_w, projw_bf, 1327104 / 8);

    // QKV GEMM: M=8192, N=3456 (14 x 256 tiles, last tile masked), K=1152
    gemm256_bt_bias<<<dim3(14, 32), 512, 0, stream>>>(hs_bf, qkvw_bf, qkv_b, qkv_tmp, 1152, 3456, 3456);
    rope_qk<<<4608, 256, 0, stream>>>(qkv_tmp, cosb, sinb, k_buf);
    v_transpose<<<2048, 256, 0, stream>>>(qkv_tmp, v_t);
    flash_attn<<<512, 256, 0, stream>>>(qkv_tmp, k_buf, v_t, attn);
    gemm_bt_bias<true><<<dim3(9, 64), 256, 0, stream>>>(attn, projw_bf, proj_b, out, 8192, 1152, 1152);
}